// Round 2
// baseline (271.516 us; speedup 1.0000x reference)
//
#include <hip/hip_runtime.h>
#include <stdint.h>
#include <math.h>

#define SLEN 2048
#define EPT 32               // elements per lane: one wave owns a full row
#define NTHREADS 256         // 4 waves = 4 independent rows per block
#define ROWS_PER_BLOCK 4
#define TOKENS_PER_OUT 8388608   // 1024*4*2048

// ---------- Threefry-2x32, 20 rounds, matches jax._src.prng ----------
__host__ __device__ __forceinline__ void tf2x32(uint32_t k0, uint32_t k1,
                                                uint32_t x0, uint32_t x1,
                                                uint32_t &o0, uint32_t &o1) {
  uint32_t ks2 = 0x1BD11BDAu ^ k0 ^ k1;
  x0 += k0; x1 += k1;
#define TFR(r) { x0 += x1; x1 = (x1 << (r)) | (x1 >> (32 - (r))); x1 ^= x0; }
  TFR(13) TFR(15) TFR(26) TFR(6)
  x0 += k1;  x1 += ks2 + 1u;
  TFR(17) TFR(29) TFR(16) TFR(24)
  x0 += ks2; x1 += k0 + 2u;
  TFR(13) TFR(15) TFR(26) TFR(6)
  x0 += k0;  x1 += k1 + 3u;
  TFR(17) TFR(29) TFR(16) TFR(24)
  x0 += k1;  x1 += ks2 + 4u;
  TFR(13) TFR(15) TFR(26) TFR(6)
  x0 += ks2; x1 += k0 + 5u;
#undef TFR
  o0 = x0; o1 = x1;
}

// 4 independent threefry streams; sched_barrier after each round keeps the
// 4-wide interleave intact through the machine scheduler.
__device__ __forceinline__ void tf4_bits(uint32_t k0, uint32_t k1,
                                         uint32_t cbase, uint32_t bits[4]) {
  const uint32_t ks2 = 0x1BD11BDAu ^ k0 ^ k1;
  uint32_t x0[4], x1[4];
#pragma unroll
  for (int i = 0; i < 4; ++i) { x0[i] = k0; x1[i] = (cbase + (uint32_t)i) + k1; }
#define TFR4(r)                                                         \
  _Pragma("unroll")                                                     \
  for (int i = 0; i < 4; ++i) {                                         \
    x0[i] += x1[i];                                                     \
    x1[i] = (x1[i] << (r)) | (x1[i] >> (32 - (r)));                     \
    x1[i] ^= x0[i];                                                     \
  }                                                                     \
  __builtin_amdgcn_sched_barrier(0);
#define INJ4(a, b)                                                      \
  _Pragma("unroll")                                                     \
  for (int i = 0; i < 4; ++i) { x0[i] += (a); x1[i] += (b); }
  TFR4(13) TFR4(15) TFR4(26) TFR4(6)
  INJ4(k1, ks2 + 1u)
  TFR4(17) TFR4(29) TFR4(16) TFR4(24)
  INJ4(ks2, k0 + 2u)
  TFR4(13) TFR4(15) TFR4(26) TFR4(6)
  INJ4(k0, k1 + 3u)
  TFR4(17) TFR4(29) TFR4(16) TFR4(24)
  INJ4(k1, ks2 + 4u)
  TFR4(13) TFR4(15) TFR4(26) TFR4(6)
  INJ4(ks2, k0 + 5u)
#undef TFR4
#undef INJ4
#pragma unroll
  for (int i = 0; i < 4; ++i) bits[i] = x0[i] ^ x1[i];
}

__device__ __forceinline__ float u01_from_bits(uint32_t bits) {
  return __uint_as_float((bits >> 9) | 0x3F800000u) - 1.0f;
}

#define SBAR() __builtin_amdgcn_sched_barrier(0)

// 8 correctly-rounded-quality f32 logs (positive normal f32 inputs), staged
// 8-wide with hard sched barriers so dependent f64 ops sit ~8 instrs apart.
// Values are BIT-IDENTICAL to the verified scalar math of R3-R5:
//   x = 2^e * m, m in [sqrt2/2, sqrt2)  (normalization done on the f32 bits:
//   mant > 0x3504F3  <=>  1.mant > sqrt2_f64, exact for 23-bit mantissas),
//   r = (m-1)*rcp(m+1) w/ 1 Newton, log = e*ln2 + 2r*(1 + t/3 + .. + t^6/13).
__device__ __forceinline__ void log8_cr(const float x[8], float out[8]) {
#pragma clang fp contract(off)
  double m[8]; int e[8];
#pragma unroll
  for (int i = 0; i < 8; ++i) {
    uint32_t xb   = __float_as_uint(x[i]);
    uint32_t mant = xb & 0x7FFFFFu;
    int      ee   = (int)(xb >> 23) - 127;
    bool     big  = mant > 0x3504F3u;          // m > sqrt(2)
    e[i] = ee + (big ? 1 : 0);
    uint32_t hi = (big ? 0x3FE00000u : 0x3FF00000u) | (mant >> 3);
    uint32_t lo = mant << 29;
    m[i] = __longlong_as_double(((long long)hi << 32) | (long long)lo);
  }
  SBAR();
  double mp1[8];
#pragma unroll
  for (int i = 0; i < 8; ++i) mp1[i] = m[i] + 1.0;
  SBAR();
  double y[8];
#pragma unroll
  for (int i = 0; i < 8; ++i) y[i] = __builtin_amdgcn_rcp(mp1[i]);
  SBAR();
#pragma unroll
  for (int i = 0; i < 8; ++i) y[i] = fma(fma(-mp1[i], y[i], 1.0), y[i], y[i]);
  SBAR();
  double r[8];
#pragma unroll
  for (int i = 0; i < 8; ++i) r[i] = (m[i] - 1.0) * y[i];
  SBAR();
  double t[8];
#pragma unroll
  for (int i = 0; i < 8; ++i) t[i] = r[i] * r[i];
  SBAR();
  double p[8];
#pragma unroll
  for (int i = 0; i < 8; ++i) p[i] = fma(0.07692307692307693, t[i], 0.09090909090909091);
  SBAR();
#pragma unroll
  for (int i = 0; i < 8; ++i) p[i] = fma(p[i], t[i], 0.1111111111111111);
  SBAR();
#pragma unroll
  for (int i = 0; i < 8; ++i) p[i] = fma(p[i], t[i], 0.14285714285714285);
  SBAR();
#pragma unroll
  for (int i = 0; i < 8; ++i) p[i] = fma(p[i], t[i], 0.2);
  SBAR();
#pragma unroll
  for (int i = 0; i < 8; ++i) p[i] = fma(p[i], t[i], 0.3333333333333333);
  SBAR();
#pragma unroll
  for (int i = 0; i < 8; ++i) p[i] = fma(p[i], t[i], 1.0);
  SBAR();
#pragma unroll
  for (int i = 0; i < 8; ++i) r[i] = r[i] + r[i];       // 2r (exact)
  SBAR();
#pragma unroll
  for (int i = 0; i < 8; ++i) p[i] = r[i] * p[i];       // 2r*q
  SBAR();
#pragma unroll
  for (int i = 0; i < 8; ++i)
    out[i] = (float)fma((double)e[i], 0.6931471805599453, p[i]);
}

// scalar CR log (erfinv path only; same math, unstaged)
__device__ __forceinline__ float log_cr(float x) {
#pragma clang fp contract(off)
  uint32_t xb   = __float_as_uint(x);
  uint32_t mant = xb & 0x7FFFFFu;
  int      e    = (int)(xb >> 23) - 127;
  bool     big  = mant > 0x3504F3u;
  e += big ? 1 : 0;
  uint32_t hi = (big ? 0x3FE00000u : 0x3FF00000u) | (mant >> 3);
  double m = __longlong_as_double(((long long)hi << 32) | (long long)(mant << 29));
  double mp1 = m + 1.0;
  double y = __builtin_amdgcn_rcp(mp1);
  y = fma(fma(-mp1, y, 1.0), y, y);
  double r = (m - 1.0) * y;
  double t = r * r;
  double p = fma(0.07692307692307693, t, 0.09090909090909091);
  p = fma(p, t, 0.1111111111111111);
  p = fma(p, t, 0.14285714285714285);
  p = fma(p, t, 0.2);
  p = fma(p, t, 0.3333333333333333);
  p = fma(p, t, 1.0);
  return (float)fma((double)e, 0.6931471805599453, (r + r) * p);
}

// XLA ErfInv f32 expander (Giles poly), log1p per ElementalIrEmitter::EmitLog1p
__device__ float erfinv_xla(float x) {
#pragma clang fp contract(off)
  float x2  = x * x;
  float nx2 = -x2;
  float l1p;
  if (fabsf(nx2) < 1e-4f) {
    l1p = (-0.5f * nx2 + 1.0f) * nx2;
  } else {
    l1p = log_cr(1.0f + nx2);
  }
  float w = -l1p;
  float p;
  if (w < 5.0f) {
    float ww = w - 2.5f;
    p = 2.81022636e-08f;
    p = p * ww + 3.43273939e-07f;
    p = p * ww + -3.5233877e-06f;
    p = p * ww + -4.39150654e-06f;
    p = p * ww + 0.00021858087f;
    p = p * ww + -0.00125372503f;
    p = p * ww + -0.00417768164f;
    p = p * ww + 0.246640727f;
    p = p * ww + 1.50140941f;
  } else {
    float ww = sqrtf(w) - 3.0f;
    p = -0.000200214257f;
    p = p * ww + 0.000100950558f;
    p = p * ww + 0.00134934322f;
    p = p * ww + -0.00367342844f;
    p = p * ww + 0.00573950773f;
    p = p * ww + -0.0076224613f;
    p = p * ww + 0.00943887047f;
    p = p * ww + 1.00167406f;
    p = p * ww + 2.83297682f;
  }
  return p * x;
}

// R2 rewrite: wave-per-row. R1 showed the kernel is NOT wave-supply-limited
// (occupancy 51->58 at fixed 75us): the 45% VALU idle is structural -- 9-11
// __syncthreads per block, wave0-serial scans while 3 waves wait, and convoy
// effects across homogeneous blocks. One row (2048 el) = one wave (32/lane):
// every cross-thread step (histogram, radix scan, threshold broadcast,
// tie-break) becomes wave-synchronous -> ZERO block barriers, no convoy.
// Per-wave private 256-bin hist (1KB x4), single buffer reused (DS ops from
// one wave are in-order; explicit lgkmcnt fences as belt-and-braces).
// kk/erfinv hoisted before the key pipeline so its serial chain hides.
__global__ __launch_bounds__(NTHREADS, 4)
void gumbel_topk_mask(const float* __restrict__ wfull,   // (B,C,2S) f32
                      const int*   __restrict__ attn,    // (B,C,S) i32
                      const int*   __restrict__ ids,     // (B,C,S) i32
                      int* __restrict__ out,             // 3x(B,C,S) i32 concat
                      uint32_t kg0, uint32_t kg1, uint32_t kn0, uint32_t kn1) {
#pragma clang fp contract(off)
  const int t    = threadIdx.x;
  const int lane = t & 63;
  const int wid  = t >> 6;
  const int row  = blockIdx.x * ROWS_PER_BLOCK + wid;

  __shared__ __align__(16) uint32_t hist[ROWS_PER_BLOCK][256];

  const size_t rbase = (size_t)row * SLEN;
  const size_t wbase = (size_t)row * (2 * SLEN);
  const int    base  = lane * EPT;         // contiguous 32-element chunk per lane

  // zero my wave's private histogram (4 bins per lane, wave-synchronous)
  ((uint4*)hist[wid])[lane] = make_uint4(0u, 0u, 0u, 0u);

  // ---- attention sum (pure wave reduce, no LDS) ----
  const int4* av4 = (const int4*)(attn + rbase + base);
  int psum = 0;
#pragma unroll
  for (int c = 0; c < 8; ++c) {
    int4 a = av4[c];
    psum += a.x + a.y + a.z + a.w;
  }
#pragma unroll
  for (int off = 32; off; off >>= 1) psum += __shfl_down(psum, off, 64);
  int asum = __shfl(psum, 0, 64);

  // ---- kk (num_to_mask): hoisted BEFORE the key pipeline; all lanes
  // redundantly compute the same value (uniform branches) ----
  uint32_t no0, no1;
  tf2x32(kn0, kn1, 0u, (uint32_t)row, no0, no1);
  float f0  = u01_from_bits(no0 ^ no1);
  float lo  = __uint_as_float(0xBF7FFFFFu);        // nextafter(-1,0)
  float u2  = fmaxf(lo, f0 * 2.0f + lo);           // (1-lo) rounds to 2.0f
  float z   = erfinv_xla(u2);
  float nrm = 1.4142135623730951f * z;
  float frac = 0.15f + 0.0375f * nrm;
  int kk = (int)floorf((float)asum * frac);

  // ---- key pipeline: 4 chunks x 8 elements (forced-ILP, same math as R0) ----
  uint32_t mloc[EPT];
  const float4* wv4 = (const float4*)(wfull + wbase + base);
#pragma unroll
  for (int c = 0; c < 4; ++c) {
    float4 w0 = wv4[2 * c + 0], w1 = wv4[2 * c + 1];
    uint32_t bits[8];
    tf4_bits(kg0, kg1, (uint32_t)(rbase + base + 8 * c + 0), bits + 0);
    tf4_bits(kg0, kg1, (uint32_t)(rbase + base + 8 * c + 4), bits + 4);
    SBAR();
    float wl[8] = {w0.x, w0.y, w0.z, w0.w, w1.x, w1.y, w1.z, w1.w};
    float uu[8];
#pragma unroll
    for (int e = 0; e < 8; ++e) {
      float f = u01_from_bits(bits[e]);
      uu[e] = fmaxf(1.17549435e-38f, f * 1.0f + 1.17549435e-38f);
    }
    SBAR();
    float l1[8];
    log8_cr(uu, l1);                       // log u
    float wm[8];
#pragma unroll
    for (int e = 0; e < 8; ++e) wm[e] = fmaxf(wl[e], 1e-30f);
    float lw[8];
    log8_cr(wm, lw);                       // log w
    float nl1[8];
#pragma unroll
    for (int e = 0; e < 8; ++e) nl1[e] = -l1[e];
    float l2[8];
    log8_cr(nl1, l2);                      // log(-log u); gumbel = -l2
    SBAR();
#pragma unroll
    for (int e = 0; e < 8; ++e) {
      float key = (wl[e] > 0.0f) ? (lw[e] + (-l2[e])) : -__builtin_inff();
      uint32_t kb = __float_as_uint(key);
      mloc[8 * c + e] = (kb & 0x80000000u) ? ~kb : (kb | 0x80000000u);  // monotone
    }
  }

  // ---- wave-private radix-select of the k-th largest key ----
  uint32_t T, r;
  if (kk <= 0)          { T = 0xFFFFFFFFu; r = 0u; }          // mask nothing
  else if (kk >= SLEN)  { T = 0u;          r = (uint32_t)SLEN; } // mask all
  else {
    T = 0u;
    uint32_t need = (uint32_t)kk;
    // pass-3 histogram (zero-write above is ordered before these per-wave)
    asm volatile("s_waitcnt lgkmcnt(0)" ::: "memory");
#pragma unroll
    for (int e = 0; e < EPT; ++e)
      atomicAdd(&hist[wid][mloc[e] >> 24], 1u);
    for (int p = 3; ; --p) {
      asm volatile("s_waitcnt lgkmcnt(0)" ::: "memory");   // atomics visible
      __builtin_amdgcn_wave_barrier();
      uint4 hq = ((const uint4*)hist[wid])[lane];          // bins 4*lane..+3
      uint32_t gs  = hq.x + hq.y + hq.z + hq.w;
      uint32_t sfx = gs;                                   // inclusive suffix sum
#pragma unroll
      for (int off = 1; off < 64; off <<= 1) {
        uint32_t n = __shfl_down(sfx, off, 64);
        if (lane + off < 64) sfx += n;
      }
      uint32_t Gex = sfx - gs;                             // sum over lanes > me
      uint32_t S3 = Gex;
      uint32_t S2 = S3 + hq.w;
      uint32_t S1 = S2 + hq.z;
      uint32_t S0 = S1 + hq.y;
      uint32_t hh[4] = {hq.x, hq.y, hq.z, hq.w};
      uint32_t SS[4] = {S0, S1, S2, S3};
      int haswin = 0; uint32_t binv = 0u, remv = 0u; int donev = 0;
#pragma unroll
      for (int i = 0; i < 4; ++i) {
        if (hh[i] && SS[i] < need && need <= SS[i] + hh[i]) {   // unique winner
          haswin = 1;
          binv = (uint32_t)(4 * lane + i);
          remv = need - SS[i];
          donev = (remv == hh[i]) ? 1 : 0;   // whole bin taken: low bytes stay 0
        }
      }
      unsigned long long wmask = __ballot(haswin);
      int src = (int)(__ffsll((unsigned long long)wmask) - 1);
      uint32_t bin = (uint32_t)__shfl((int)binv, src, 64);
      uint32_t rem = (uint32_t)__shfl((int)remv, src, 64);
      int     done = __shfl(donev, src, 64);
      T |= bin << (8 * p);
      need = rem;
      if (done || p == 0) { r = rem; break; }
      // clear my 4 bins (same ones I just read), then histogram digit p-1
      ((uint4*)hist[wid])[lane] = make_uint4(0u, 0u, 0u, 0u);
      asm volatile("s_waitcnt lgkmcnt(0)" ::: "memory");   // clears before atomics
      __builtin_amdgcn_wave_barrier();
      const int sh = 8 * p;
#pragma unroll
      for (int e = 0; e < EPT; ++e) {
        uint32_t m = mloc[e];
        if ((m >> sh) == (T >> sh))
          atomicAdd(&hist[wid][(m >> (sh - 8)) & 255u], 1u);
      }
    }
  }

  // ---- epilogue: stable tie-break scan (pure wave scan; lane chunks are
  // index-contiguous so lane order == index order) + masked writes ----
  int local_eq = 0;
#pragma unroll
  for (int e = 0; e < EPT; ++e) local_eq += (mloc[e] == T) ? 1 : 0;
  uint32_t v = (uint32_t)local_eq;
#pragma unroll
  for (int off = 1; off < 64; off <<= 1) {
    uint32_t n = __shfl_up(v, off, 64);
    if (lane >= off) v += n;
  }
  uint32_t excl = v - (uint32_t)local_eq;   // #eq-to-threshold before my chunk

  const int4* iv4 = (const int4*)(ids + rbase + base);
  int4* po = (int4*)(out + rbase + base);
  int4* pm = (int4*)(out + TOKENS_PER_OUT + rbase + base);
  int4* pl = (int4*)(out + 2 * TOKENS_PER_OUT + rbase + base);
#pragma unroll
  for (int c = 0; c < 4; ++c) {
    int4 i0 = iv4[2 * c + 0], i1 = iv4[2 * c + 1];
    int idv[8] = {i0.x, i0.y, i0.z, i0.w, i1.x, i1.y, i1.z, i1.w};
    int oid[8], omk[8], olb[8];
#pragma unroll
    for (int e = 0; e < 8; ++e) {
      uint32_t m = mloc[8 * c + e];
      bool eq  = (m == T);
      bool msk = (m > T) || (eq && (excl < r));
      excl += eq ? 1u : 0u;
      oid[e] = msk ? 103 : idv[e];      // MASK_ID
      omk[e] = msk ? 1 : 0;
      olb[e] = msk ? -1 : 0;
    }
    po[2 * c + 0] = make_int4(oid[0], oid[1], oid[2], oid[3]);
    po[2 * c + 1] = make_int4(oid[4], oid[5], oid[6], oid[7]);
    pm[2 * c + 0] = make_int4(omk[0], omk[1], omk[2], omk[3]);
    pm[2 * c + 1] = make_int4(omk[4], omk[5], omk[6], omk[7]);
    pl[2 * c + 0] = make_int4(olb[0], olb[1], olb[2], olb[3]);
    pl[2 * c + 1] = make_int4(olb[4], olb[5], olb[6], olb[7]);
  }
}

extern "C" void kernel_launch(void* const* d_in, const int* in_sizes, int n_in,
                              void* d_out, int out_size, void* d_ws, size_t ws_size,
                              hipStream_t stream) {
  (void)n_in; (void)d_ws; (void)ws_size; (void)out_size;
  const float* wfull = (const float*)d_in[0];   // my_attention_mask (B,C,2S)
  const int*   attn  = (const int*)d_in[1];     // attention_mask    (B,C,S)
  const int*   ids   = (const int*)d_in[2];     // input_ids         (B,C,S)
  int* out = (int*)d_out;

  // jax.random.key(42) -> (0,42); partitionable split: kg=enc(key,(0,0)), kn=enc(key,(0,1))
  uint32_t kg0, kg1, kn0, kn1, o0, o1;
  tf2x32(0u, 42u, 0u, 0u, o0, o1); kg0 = o0; kg1 = o1;
  tf2x32(0u, 42u, 0u, 1u, o0, o1); kn0 = o0; kn1 = o1;

  int rows = in_sizes[1] / SLEN;                // 4096
  hipLaunchKernelGGL(gumbel_topk_mask, dim3(rows / ROWS_PER_BLOCK), dim3(NTHREADS),
                     0, stream, wfull, attn, ids, out, kg0, kg1, kn0, kn1);
}

// Round 3
// 208.506 us; speedup vs baseline: 1.3022x; 1.3022x over previous
//
#include <hip/hip_runtime.h>
#include <stdint.h>
#include <math.h>

#define SLEN 2048
#define EPT 32               // elements per lane: one wave owns a full row
#define NTHREADS 256         // 4 waves = 4 independent rows per block
#define ROWS_PER_BLOCK 4
#define NCHUNK 8             // row = 8 chunks of 256 el (64 lanes x 4 el)
#define TOKENS_PER_OUT 8388608   // 1024*4*2048

// ---------- Threefry-2x32, 20 rounds, matches jax._src.prng ----------
__host__ __device__ __forceinline__ void tf2x32(uint32_t k0, uint32_t k1,
                                                uint32_t x0, uint32_t x1,
                                                uint32_t &o0, uint32_t &o1) {
  uint32_t ks2 = 0x1BD11BDAu ^ k0 ^ k1;
  x0 += k0; x1 += k1;
#define TFR(r) { x0 += x1; x1 = (x1 << (r)) | (x1 >> (32 - (r))); x1 ^= x0; }
  TFR(13) TFR(15) TFR(26) TFR(6)
  x0 += k1;  x1 += ks2 + 1u;
  TFR(17) TFR(29) TFR(16) TFR(24)
  x0 += ks2; x1 += k0 + 2u;
  TFR(13) TFR(15) TFR(26) TFR(6)
  x0 += k0;  x1 += k1 + 3u;
  TFR(17) TFR(29) TFR(16) TFR(24)
  x0 += k1;  x1 += ks2 + 4u;
  TFR(13) TFR(15) TFR(26) TFR(6)
  x0 += ks2; x1 += k0 + 5u;
#undef TFR
  o0 = x0; o1 = x1;
}

// 4 independent threefry streams; sched_barrier after each round keeps the
// 4-wide interleave intact through the machine scheduler.
__device__ __forceinline__ void tf4_bits(uint32_t k0, uint32_t k1,
                                         uint32_t cbase, uint32_t bits[4]) {
  const uint32_t ks2 = 0x1BD11BDAu ^ k0 ^ k1;
  uint32_t x0[4], x1[4];
#pragma unroll
  for (int i = 0; i < 4; ++i) { x0[i] = k0; x1[i] = (cbase + (uint32_t)i) + k1; }
#define TFR4(r)                                                         \
  _Pragma("unroll")                                                     \
  for (int i = 0; i < 4; ++i) {                                         \
    x0[i] += x1[i];                                                     \
    x1[i] = (x1[i] << (r)) | (x1[i] >> (32 - (r)));                     \
    x1[i] ^= x0[i];                                                     \
  }                                                                     \
  __builtin_amdgcn_sched_barrier(0);
#define INJ4(a, b)                                                      \
  _Pragma("unroll")                                                     \
  for (int i = 0; i < 4; ++i) { x0[i] += (a); x1[i] += (b); }
  TFR4(13) TFR4(15) TFR4(26) TFR4(6)
  INJ4(k1, ks2 + 1u)
  TFR4(17) TFR4(29) TFR4(16) TFR4(24)
  INJ4(ks2, k0 + 2u)
  TFR4(13) TFR4(15) TFR4(26) TFR4(6)
  INJ4(k0, k1 + 3u)
  TFR4(17) TFR4(29) TFR4(16) TFR4(24)
  INJ4(k1, ks2 + 4u)
  TFR4(13) TFR4(15) TFR4(26) TFR4(6)
  INJ4(ks2, k0 + 5u)
#undef TFR4
#undef INJ4
#pragma unroll
  for (int i = 0; i < 4; ++i) bits[i] = x0[i] ^ x1[i];
}

__device__ __forceinline__ float u01_from_bits(uint32_t bits) {
  return __uint_as_float((bits >> 9) | 0x3F800000u) - 1.0f;
}

#define SBAR() __builtin_amdgcn_sched_barrier(0)

// 8 correctly-rounded-quality f32 logs (positive normal f32 inputs), staged
// 8-wide with hard sched barriers so dependent f64 ops sit ~8 instrs apart.
// Bit-identical to the verified scalar math:
//   x = 2^e * m, m in [sqrt2/2, sqrt2), r = (m-1)*rcp(m+1) w/ 1 Newton,
//   log = e*ln2 + 2r*(1 + t/3 + .. + t^6/13).
__device__ __forceinline__ void log8_cr(const float x[8], float out[8]) {
#pragma clang fp contract(off)
  double m[8]; int e[8];
#pragma unroll
  for (int i = 0; i < 8; ++i) {
    uint32_t xb   = __float_as_uint(x[i]);
    uint32_t mant = xb & 0x7FFFFFu;
    int      ee   = (int)(xb >> 23) - 127;
    bool     big  = mant > 0x3504F3u;          // m > sqrt(2)
    e[i] = ee + (big ? 1 : 0);
    uint32_t hi = (big ? 0x3FE00000u : 0x3FF00000u) | (mant >> 3);
    uint32_t lo = mant << 29;
    m[i] = __longlong_as_double(((long long)hi << 32) | (long long)lo);
  }
  SBAR();
  double mp1[8];
#pragma unroll
  for (int i = 0; i < 8; ++i) mp1[i] = m[i] + 1.0;
  SBAR();
  double y[8];
#pragma unroll
  for (int i = 0; i < 8; ++i) y[i] = __builtin_amdgcn_rcp(mp1[i]);
  SBAR();
#pragma unroll
  for (int i = 0; i < 8; ++i) y[i] = fma(fma(-mp1[i], y[i], 1.0), y[i], y[i]);
  SBAR();
  double r[8];
#pragma unroll
  for (int i = 0; i < 8; ++i) r[i] = (m[i] - 1.0) * y[i];
  SBAR();
  double t[8];
#pragma unroll
  for (int i = 0; i < 8; ++i) t[i] = r[i] * r[i];
  SBAR();
  double p[8];
#pragma unroll
  for (int i = 0; i < 8; ++i) p[i] = fma(0.07692307692307693, t[i], 0.09090909090909091);
  SBAR();
#pragma unroll
  for (int i = 0; i < 8; ++i) p[i] = fma(p[i], t[i], 0.1111111111111111);
  SBAR();
#pragma unroll
  for (int i = 0; i < 8; ++i) p[i] = fma(p[i], t[i], 0.14285714285714285);
  SBAR();
#pragma unroll
  for (int i = 0; i < 8; ++i) p[i] = fma(p[i], t[i], 0.2);
  SBAR();
#pragma unroll
  for (int i = 0; i < 8; ++i) p[i] = fma(p[i], t[i], 0.3333333333333333);
  SBAR();
#pragma unroll
  for (int i = 0; i < 8; ++i) p[i] = fma(p[i], t[i], 1.0);
  SBAR();
#pragma unroll
  for (int i = 0; i < 8; ++i) r[i] = r[i] + r[i];       // 2r (exact)
  SBAR();
#pragma unroll
  for (int i = 0; i < 8; ++i) p[i] = r[i] * p[i];       // 2r*q
  SBAR();
#pragma unroll
  for (int i = 0; i < 8; ++i)
    out[i] = (float)fma((double)e[i], 0.6931471805599453, p[i]);
}

// scalar CR log (erfinv path only; same math, unstaged)
__device__ __forceinline__ float log_cr(float x) {
#pragma clang fp contract(off)
  uint32_t xb   = __float_as_uint(x);
  uint32_t mant = xb & 0x7FFFFFu;
  int      e    = (int)(xb >> 23) - 127;
  bool     big  = mant > 0x3504F3u;
  e += big ? 1 : 0;
  uint32_t hi = (big ? 0x3FE00000u : 0x3FF00000u) | (mant >> 3);
  double m = __longlong_as_double(((long long)hi << 32) | (long long)(mant << 29));
  double mp1 = m + 1.0;
  double y = __builtin_amdgcn_rcp(mp1);
  y = fma(fma(-mp1, y, 1.0), y, y);
  double r = (m - 1.0) * y;
  double t = r * r;
  double p = fma(0.07692307692307693, t, 0.09090909090909091);
  p = fma(p, t, 0.1111111111111111);
  p = fma(p, t, 0.14285714285714285);
  p = fma(p, t, 0.2);
  p = fma(p, t, 0.3333333333333333);
  p = fma(p, t, 1.0);
  return (float)fma((double)e, 0.6931471805599453, (r + r) * p);
}

// XLA ErfInv f32 expander (Giles poly), log1p per ElementalIrEmitter::EmitLog1p
__device__ float erfinv_xla(float x) {
#pragma clang fp contract(off)
  float x2  = x * x;
  float nx2 = -x2;
  float l1p;
  if (fabsf(nx2) < 1e-4f) {
    l1p = (-0.5f * nx2 + 1.0f) * nx2;
  } else {
    l1p = log_cr(1.0f + nx2);
  }
  float w = -l1p;
  float p;
  if (w < 5.0f) {
    float ww = w - 2.5f;
    p = 2.81022636e-08f;
    p = p * ww + 3.43273939e-07f;
    p = p * ww + -3.5233877e-06f;
    p = p * ww + -4.39150654e-06f;
    p = p * ww + 0.00021858087f;
    p = p * ww + -0.00125372503f;
    p = p * ww + -0.00417768164f;
    p = p * ww + 0.246640727f;
    p = p * ww + 1.50140941f;
  } else {
    float ww = sqrtf(w) - 3.0f;
    p = -0.000200214257f;
    p = p * ww + 0.000100950558f;
    p = p * ww + 0.00134934322f;
    p = p * ww + -0.00367342844f;
    p = p * ww + 0.00573950773f;
    p = p * ww + -0.0076224613f;
    p = p * ww + 0.00943887047f;
    p = p * ww + 1.00167406f;
    p = p * ww + 2.83297682f;
  }
  return p * x;
}

// R3: wave-per-row (R2's barrier-free structure) + COALESCED lane-interleaved
// layout. R2's regression was pure Guideline-2: base=lane*128B gave every
// load/store a 128B inter-lane stride (WRITE_SIZE 98->125MB = RMW proof,
// FETCH 49->93MB). Now lane i owns elements 256*j + 4*i .. +3 (8 chunks):
// every float4/int4 access is one contiguous 1KB wave transaction. RNG
// counters stay consecutive per tf4_bits. Tie-break needs index-order across
// chunks: 4 packed 16-bit-field wave scans + per-chunk totals.
__global__ __launch_bounds__(NTHREADS, 4)
void gumbel_topk_mask(const float* __restrict__ wfull,   // (B,C,2S) f32
                      const int*   __restrict__ attn,    // (B,C,S) i32
                      const int*   __restrict__ ids,     // (B,C,S) i32
                      int* __restrict__ out,             // 3x(B,C,S) i32 concat
                      uint32_t kg0, uint32_t kg1, uint32_t kn0, uint32_t kn1) {
#pragma clang fp contract(off)
  const int t    = threadIdx.x;
  const int lane = t & 63;
  const int wid  = t >> 6;
  const int row  = blockIdx.x * ROWS_PER_BLOCK + wid;

  __shared__ __align__(16) uint32_t hist[ROWS_PER_BLOCK][256];

  const size_t rbase = (size_t)row * SLEN;
  const size_t wbase = (size_t)row * (2 * SLEN);

  // zero my wave's private histogram (4 bins per lane, wave-synchronous)
  ((uint4*)hist[wid])[lane] = make_uint4(0u, 0u, 0u, 0u);

  const int4*   av4 = (const int4*)(attn + rbase);
  const float4* wv4 = (const float4*)(wfull + wbase);
  const int4*   iv4 = (const int4*)(ids + rbase);

  // ---- issue attn + w loads up front (coalesced: lane stride 16B) ----
  int psum = 0;
#pragma unroll
  for (int j = 0; j < NCHUNK; ++j) {
    int4 a = av4[64 * j + lane];
    psum += a.x + a.y + a.z + a.w;
  }
  float4 wv[NCHUNK];
#pragma unroll
  for (int j = 0; j < NCHUNK; ++j) wv[j] = wv4[64 * j + lane];

  // ---- frac (load-independent; hides the load latency) ----
  uint32_t no0, no1;
  tf2x32(kn0, kn1, 0u, (uint32_t)row, no0, no1);
  float f0  = u01_from_bits(no0 ^ no1);
  float lo  = __uint_as_float(0xBF7FFFFFu);        // nextafter(-1,0)
  float u2  = fmaxf(lo, f0 * 2.0f + lo);           // (1-lo) rounds to 2.0f
  float z   = erfinv_xla(u2);
  float nrm = 1.4142135623730951f * z;
  float frac = 0.15f + 0.0375f * nrm;

  // ---- attention sum (pure wave reduce) -> kk ----
#pragma unroll
  for (int off = 32; off; off >>= 1) psum += __shfl_down(psum, off, 64);
  int asum = __shfl(psum, 0, 64);
  int kk = (int)floorf((float)asum * frac);

  // ---- key pipeline: 4 chunk-pairs x 8 elements (forced-ILP) ----
  // mloc[4*j + e] <=> chunk j (indices 256j+4*lane), element e.
  uint32_t mloc[EPT];
#pragma unroll
  for (int c = 0; c < 4; ++c) {
    uint32_t bits[8];
    tf4_bits(kg0, kg1, (uint32_t)(rbase + 256 * (2 * c)     + 4 * lane), bits + 0);
    tf4_bits(kg0, kg1, (uint32_t)(rbase + 256 * (2 * c + 1) + 4 * lane), bits + 4);
    SBAR();
    float4 wa = wv[2 * c], wb = wv[2 * c + 1];
    float wl[8] = {wa.x, wa.y, wa.z, wa.w, wb.x, wb.y, wb.z, wb.w};
    float uu[8];
#pragma unroll
    for (int e = 0; e < 8; ++e) {
      float f = u01_from_bits(bits[e]);
      uu[e] = fmaxf(1.17549435e-38f, f * 1.0f + 1.17549435e-38f);
    }
    SBAR();
    float l1[8];
    log8_cr(uu, l1);                       // log u
    float wm[8];
#pragma unroll
    for (int e = 0; e < 8; ++e) wm[e] = fmaxf(wl[e], 1e-30f);
    float lw[8];
    log8_cr(wm, lw);                       // log w
    float nl1[8];
#pragma unroll
    for (int e = 0; e < 8; ++e) nl1[e] = -l1[e];
    float l2[8];
    log8_cr(nl1, l2);                      // log(-log u); gumbel = -l2
    SBAR();
#pragma unroll
    for (int e = 0; e < 8; ++e) {
      float key = (wl[e] > 0.0f) ? (lw[e] + (-l2[e])) : -__builtin_inff();
      uint32_t kb = __float_as_uint(key);
      mloc[8 * c + e] = (kb & 0x80000000u) ? ~kb : (kb | 0x80000000u);  // monotone
    }
  }

  // ids loads: issue now, consumed in epilogue (latency hidden under select)
  int4 idsv[NCHUNK];
#pragma unroll
  for (int j = 0; j < NCHUNK; ++j) idsv[j] = iv4[64 * j + lane];

  // ---- wave-private radix-select of the k-th largest key ----
  uint32_t T, r;
  if (kk <= 0)          { T = 0xFFFFFFFFu; r = 0u; }             // mask nothing
  else if (kk >= SLEN)  { T = 0u;          r = (uint32_t)SLEN; } // mask all
  else {
    T = 0u;
    uint32_t need = (uint32_t)kk;
    asm volatile("s_waitcnt lgkmcnt(0)" ::: "memory");   // zeros done
#pragma unroll
    for (int e = 0; e < EPT; ++e)
      atomicAdd(&hist[wid][mloc[e] >> 24], 1u);
    for (int p = 3; ; --p) {
      asm volatile("s_waitcnt lgkmcnt(0)" ::: "memory");   // atomics visible
      __builtin_amdgcn_wave_barrier();
      uint4 hq = ((const uint4*)hist[wid])[lane];          // bins 4*lane..+3
      uint32_t gs  = hq.x + hq.y + hq.z + hq.w;
      uint32_t sfx = gs;                                   // inclusive suffix sum
#pragma unroll
      for (int off = 1; off < 64; off <<= 1) {
        uint32_t n = __shfl_down(sfx, off, 64);
        if (lane + off < 64) sfx += n;
      }
      uint32_t Gex = sfx - gs;                             // sum over lanes > me
      uint32_t S3 = Gex;
      uint32_t S2 = S3 + hq.w;
      uint32_t S1 = S2 + hq.z;
      uint32_t S0 = S1 + hq.y;
      uint32_t hh[4] = {hq.x, hq.y, hq.z, hq.w};
      uint32_t SS[4] = {S0, S1, S2, S3};
      int haswin = 0; uint32_t binv = 0u, remv = 0u; int donev = 0;
#pragma unroll
      for (int i = 0; i < 4; ++i) {
        if (hh[i] && SS[i] < need && need <= SS[i] + hh[i]) {   // unique winner
          haswin = 1;
          binv = (uint32_t)(4 * lane + i);
          remv = need - SS[i];
          donev = (remv == hh[i]) ? 1 : 0;   // whole bin taken: low bytes stay 0
        }
      }
      unsigned long long wmask = __ballot(haswin);
      int src = (int)(__ffsll((unsigned long long)wmask) - 1);
      uint32_t bin = (uint32_t)__shfl((int)binv, src, 64);
      uint32_t rem = (uint32_t)__shfl((int)remv, src, 64);
      int     done = __shfl(donev, src, 64);
      T |= bin << (8 * p);
      need = rem;
      if (done || p == 0) { r = rem; break; }
      // clear my 4 bins (same ones I just read), then histogram digit p-1
      ((uint4*)hist[wid])[lane] = make_uint4(0u, 0u, 0u, 0u);
      asm volatile("s_waitcnt lgkmcnt(0)" ::: "memory");   // clears before atomics
      __builtin_amdgcn_wave_barrier();
      const int sh = 8 * p;
#pragma unroll
      for (int e = 0; e < EPT; ++e) {
        uint32_t m = mloc[e];
        if ((m >> sh) == (T >> sh))
          atomicAdd(&hist[wid][(m >> (sh - 8)) & 255u], 1u);
      }
    }
  }

  // ---- stable tie-break in INDEX order across interleaved chunks ----
  // cnt[j] = my eq-count in chunk j; 4 packed scans (16-bit fields, max 256).
  uint32_t cnt[NCHUNK];
#pragma unroll
  for (int j = 0; j < NCHUNK; ++j) {
    uint32_t c = 0;
#pragma unroll
    for (int e = 0; e < 4; ++e) c += (mloc[4 * j + e] == T) ? 1u : 0u;
    cnt[j] = c;
  }
  uint32_t incl[4];
#pragma unroll
  for (int q = 0; q < 4; ++q) incl[q] = cnt[2 * q] | (cnt[2 * q + 1] << 16);
#pragma unroll
  for (int off = 1; off < 64; off <<= 1) {
#pragma unroll
    for (int q = 0; q < 4; ++q) {
      uint32_t n = __shfl_up(incl[q], off, 64);
      if (lane >= off) incl[q] += n;
    }
  }
  uint32_t Spre[NCHUNK], tot[NCHUNK];
#pragma unroll
  for (int q = 0; q < 4; ++q) {
    uint32_t t63 = (uint32_t)__shfl((int)incl[q], 63, 64);
    tot[2 * q]      = t63 & 0xFFFFu;
    tot[2 * q + 1]  = t63 >> 16;
    Spre[2 * q]     = (incl[q] & 0xFFFFu) - cnt[2 * q];
    Spre[2 * q + 1] = (incl[q] >> 16)     - cnt[2 * q + 1];
  }

  // ---- epilogue: masked writes (coalesced) ----
  int4* po = (int4*)(out + rbase);
  int4* pm = (int4*)(out + TOKENS_PER_OUT + rbase);
  int4* pl = (int4*)(out + 2 * TOKENS_PER_OUT + rbase);
  uint32_t C = 0;   // eq-count in chunks before j (uniform across lanes)
#pragma unroll
  for (int j = 0; j < NCHUNK; ++j) {
    uint32_t excl = C + Spre[j];
    int4 iv = idsv[j];
    int idv[4] = {iv.x, iv.y, iv.z, iv.w};
    int oid[4], omk[4], olb[4];
#pragma unroll
    for (int e = 0; e < 4; ++e) {
      uint32_t m = mloc[4 * j + e];
      bool eq  = (m == T);
      bool msk = (m > T) || (eq && (excl < r));
      excl += eq ? 1u : 0u;
      oid[e] = msk ? 103 : idv[e];      // MASK_ID
      omk[e] = msk ? 1 : 0;
      olb[e] = msk ? -1 : 0;
    }
    po[64 * j + lane] = make_int4(oid[0], oid[1], oid[2], oid[3]);
    pm[64 * j + lane] = make_int4(omk[0], omk[1], omk[2], omk[3]);
    pl[64 * j + lane] = make_int4(olb[0], olb[1], olb[2], olb[3]);
    C += tot[j];
  }
}

extern "C" void kernel_launch(void* const* d_in, const int* in_sizes, int n_in,
                              void* d_out, int out_size, void* d_ws, size_t ws_size,
                              hipStream_t stream) {
  (void)n_in; (void)d_ws; (void)ws_size; (void)out_size;
  const float* wfull = (const float*)d_in[0];   // my_attention_mask (B,C,2S)
  const int*   attn  = (const int*)d_in[1];     // attention_mask    (B,C,S)
  const int*   ids   = (const int*)d_in[2];     // input_ids         (B,C,S)
  int* out = (int*)d_out;

  // jax.random.key(42) -> (0,42); partitionable split: kg=enc(key,(0,0)), kn=enc(key,(0,1))
  uint32_t kg0, kg1, kn0, kn1, o0, o1;
  tf2x32(0u, 42u, 0u, 0u, o0, o1); kg0 = o0; kg1 = o1;
  tf2x32(0u, 42u, 0u, 1u, o0, o1); kn0 = o0; kn1 = o1;

  int rows = in_sizes[1] / SLEN;                // 4096
  hipLaunchKernelGGL(gumbel_topk_mask, dim3(rows / ROWS_PER_BLOCK), dim3(NTHREADS),
                     0, stream, wfull, attn, ids, out, kg0, kg1, kn0, kn1);
}